// Round 5
// baseline (1148.135 us; speedup 1.0000x reference)
//
#include <hip/hip_runtime.h>

// ---------------------------------------------------------------------------
// YOLOv2 head on MI355X (gfx950).
// conv1 3x3 (512->1024) + BN + leaky -> conv2 1x1 (1024->425) + bias -> decode
// fp16 3-term split GEMM (ah*bh + ah*bl + al*bh) for fp32-class accuracy.
// R5: 32x32x16 MFMA (half the instructions, faster pipe), fragment-order LDS
// chunks (lane-linear conflict-free reads, 24 instead of 32 b128/wave/K-tile),
// 2 phases per K-tile with counted vmcnt(4).
// LDS chunk = 1 KB holding one (32-row x 16-k) fragment slab in exact MFMA
// read order: elem(lane l) = l*8  (rows l&31, k-half l>>5).
// ---------------------------------------------------------------------------

typedef _Float16 f16;
typedef _Float16 f16x8 __attribute__((ext_vector_type(8)));
typedef _Float16 f16x4v __attribute__((ext_vector_type(4)));
typedef float    f32x16 __attribute__((ext_vector_type(16)));

__device__ __forceinline__ void gload16(const f16* g, f16* l) {
  __builtin_amdgcn_global_load_lds(
      (const __attribute__((address_space(1))) void*)g,
      (__attribute__((address_space(3))) void*)l, 16, 0, 0);
}

#define MFMA32(a, b, c) __builtin_amdgcn_mfma_f32_32x32x16_f16(a, b, c, 0, 0, 0)
#define ASM_VMCNT(N) asm volatile("s_waitcnt vmcnt(" #N ")" ::: "memory")
#define SBAR()                           \
  {                                      \
    __builtin_amdgcn_s_barrier();        \
    __builtin_amdgcn_sched_barrier(0);   \
  }

// LDS region bases (f16 elements): each region = 2 bufs x 16 chunks x 512
#define R_AH 0
#define R_AL 16384
#define R_BH 32768
#define R_BL 49152

// anchors
__device__ const float c_AW[5] = {42.f, 98.f, 180.f, 300.f, 400.f};
__device__ const float c_AH_[5] = {45.f, 130.f, 260.f, 180.f, 400.f};

// ---------------------------------------------------------------------------
__global__ void prep_misc(const float* __restrict__ g, const float* __restrict__ be,
                          const float* __restrict__ mn, const float* __restrict__ vr,
                          const float* __restrict__ b2,
                          float* __restrict__ scale, float* __restrict__ shift,
                          float* __restrict__ bias) {
  int i = threadIdx.x;  // 1024 threads
  float s = g[i] / sqrtf(vr[i] + 1e-5f);
  shift[i] = be[i] - mn[i] * s;
  scale[i] = s * (1.0f / 1024.0f);
  if (i < 512) bias[i] = (i < 425) ? b2[i] : 0.f;
}

__global__ __launch_bounds__(256) void prep_w1(const float* __restrict__ w,
                                               f16* __restrict__ Ah, f16* __restrict__ Al) {
  const int co = blockIdx.x;
  const int k = blockIdx.y * 256 + threadIdx.x;  // < 4608
  const int ky = k / 1536, rem = k - ky * 1536;
  const int kx = rem >> 9, ci = rem & 511;
  float v = w[((co * 512 + ci) * 3 + ky) * 3 + kx] * 1024.f;
  f16 h = (f16)v;
  Ah[(long)co * 4608 + k] = h;
  Al[(long)co * 4608 + k] = (f16)(v - (float)h);
}

__global__ __launch_bounds__(256) void prep_w2(const float* __restrict__ w,
                                               f16* __restrict__ Ah, f16* __restrict__ Al) {
  const int co = blockIdx.x;                      // < 512
  const int ci = blockIdx.y * 256 + threadIdx.x;  // < 1024
  float v = (co < 425) ? w[co * 1024 + ci] * 1024.f : 0.f;
  f16 h = (f16)v;
  Ah[co * 1024 + ci] = h;
  Al[co * 1024 + ci] = (f16)(v - (float)h);
}

__global__ __launch_bounds__(256) void prep_feat(const float* __restrict__ f,
                                                 f16* __restrict__ fph, f16* __restrict__ fpl) {
  __shared__ float lds[256][33];
  const int y = blockIdx.x, b = blockIdx.y, t = threadIdx.x;
  const int xx = t & 31, cig = t >> 5;
  const float* src = f + ((long)b * 512) * 1024 + y * 32;

  for (int half = 0; half < 2; ++half) {
    const int cibase = half * 256;
    for (int rep = 0; rep < 32; ++rep) {
      int ci = rep * 8 + cig;
      lds[ci][xx] = src[(long)(cibase + ci) * 1024 + xx];
    }
    __syncthreads();
    const long rowbase = ((long)(b * 34) + (y + 1)) * 34 + 1;
    for (int xp = 0; xp < 32; ++xp) {
      float v = lds[t][xp];
      f16 h = (f16)v;
      long o = (rowbase + xp) * 512 + cibase + t;
      fph[o] = h;
      fpl[o] = (f16)(v - (float)h);
    }
    __syncthreads();
  }
}

// ---------------------------------------------------------------------------
// gemm1: C[1024][32768] = A1(1024x4608) * im2col(features) + BN + leaky.
// 256x256 tile, 8 waves (2Mx4N, per-wave 128x64 of 32x32 frags), BK=32,
// 2 phases/K-tile (one per k-step of 16), double-buffered LDS, vmcnt(4).
// grid (128 n-tiles, 4 m-tiles), block 512.
// ---------------------------------------------------------------------------
__global__ __launch_bounds__(512, 2) void gemm1(
    const f16* __restrict__ A1h, const f16* __restrict__ A1l,
    const f16* __restrict__ Bh, const f16* __restrict__ Bl,
    const float* __restrict__ scale, const float* __restrict__ shift,
    f16* __restrict__ xth, f16* __restrict__ xtl) {
  __shared__ __align__(16) f16 S[65536];  // 128 KiB
  const int tid = threadIdx.x;
  const int l = tid & 63, w = tid >> 6;
  const int wm = w >> 2, wn = w & 3;  // 2 x 4 waves; per-wave 128(M) x 64(N)
  const int l31 = l & 31, lh = l >> 5;
  const int nt = blockIdx.x, mt = blockIdx.y;
  const int n0 = nt * 256, co0 = mt * 256;
  const int b = n0 >> 10, y0 = (n0 & 1023) >> 5;

  // stage: wave w owns row/col unit u=w (32 rows/cols), both ksteps.
  const long aSrc = (long)(co0 + 32 * w + l31) * 4608 + 8 * lh;
  const long bSrc = ((long)(b * 34 + y0 + w) * 34 + l31) * 512 + 8 * lh;
  const int dA = (w * 2) * 512;  // wave-uniform LDS chunk base (s added)
  const int lro = l * 8;         // lane-linear read/write offset within chunk

  f32x16 acc[4][2] = {};  // [mf][nf]
  f16x8 ah[4], al[4], bh[2], bl[2];

  // prologue: stage tile 0, both ksteps (order s0 quad, then s1 quad)
  gload16(A1h + aSrc, &S[R_AH + dA]);
  gload16(A1l + aSrc, &S[R_AL + dA]);
  gload16(Bh + bSrc, &S[R_BH + dA]);
  gload16(Bl + bSrc, &S[R_BL + dA]);
  gload16(A1h + aSrc + 16, &S[R_AH + dA + 512]);
  gload16(A1l + aSrc + 16, &S[R_AL + dA + 512]);
  gload16(Bh + bSrc + 16, &S[R_BH + dA + 512]);
  gload16(Bl + bSrc + 16, &S[R_BL + dA + 512]);
  ASM_VMCNT(4);  // own s0 quad done; barrier syncs all waves' s0
  SBAR();

  for (int t = 0; t < 144; ++t) {
    const int cb = (t & 1) << 13;  // current buf (f16 elems)
    const int nb = 8192 - cb;      // next buf
    const int s1t = (t < 143) ? t + 1 : t;  // clamped prefetch tile
    const int ky1 = s1t / 48, r1 = s1t - ky1 * 48;
    const int kx1 = r1 >> 4, ci1 = (r1 & 15) << 5;
    const long kAn = (long)s1t * 32;
    const long kBn = (long)(ky1 * 34 + kx1) * 512 + ci1;

    // ======== P0 (kstep s=0) ========
    // stage next-tile s0 first (max latency cover)
    gload16(A1h + aSrc + kAn, &S[R_AH + nb + dA]);
    gload16(A1l + aSrc + kAn, &S[R_AL + nb + dA]);
    gload16(Bh + bSrc + kBn, &S[R_BH + nb + dA]);
    gload16(Bl + bSrc + kBn, &S[R_BL + nb + dA]);
    // fragment reads (current tile, s=0): lane-linear, conflict-free
#pragma unroll
    for (int mf = 0; mf < 4; ++mf) {
      const int ch = ((wm * 4 + mf) * 2) * 512;
      ah[mf] = *(const f16x8*)&S[R_AH + cb + ch + lro];
      al[mf] = *(const f16x8*)&S[R_AL + cb + ch + lro];
    }
#pragma unroll
    for (int nf = 0; nf < 2; ++nf) {
      const int ch = ((wn * 2 + nf) * 2) * 512;
      bh[nf] = *(const f16x8*)&S[R_BH + cb + ch + lro];
      bl[nf] = *(const f16x8*)&S[R_BL + cb + ch + lro];
    }
    ASM_VMCNT(4);  // leaves exactly the 4 loads just issued
    SBAR();
    __builtin_amdgcn_s_setprio(1);
#pragma unroll
    for (int mf = 0; mf < 4; ++mf)
#pragma unroll
      for (int nf = 0; nf < 2; ++nf) {
        acc[mf][nf] = MFMA32(ah[mf], bh[nf], acc[mf][nf]);
        acc[mf][nf] = MFMA32(ah[mf], bl[nf], acc[mf][nf]);
        acc[mf][nf] = MFMA32(al[mf], bh[nf], acc[mf][nf]);
      }
    __builtin_amdgcn_s_setprio(0);
    SBAR();

    // ======== P1 (kstep s=1) ========
    gload16(A1h + aSrc + kAn + 16, &S[R_AH + nb + dA + 512]);
    gload16(A1l + aSrc + kAn + 16, &S[R_AL + nb + dA + 512]);
    gload16(Bh + bSrc + kBn + 16, &S[R_BH + nb + dA + 512]);
    gload16(Bl + bSrc + kBn + 16, &S[R_BL + nb + dA + 512]);
#pragma unroll
    for (int mf = 0; mf < 4; ++mf) {
      const int ch = ((wm * 4 + mf) * 2 + 1) * 512;
      ah[mf] = *(const f16x8*)&S[R_AH + cb + ch + lro];
      al[mf] = *(const f16x8*)&S[R_AL + cb + ch + lro];
    }
#pragma unroll
    for (int nf = 0; nf < 2; ++nf) {
      const int ch = ((wn * 2 + nf) * 2 + 1) * 512;
      bh[nf] = *(const f16x8*)&S[R_BH + cb + ch + lro];
      bl[nf] = *(const f16x8*)&S[R_BL + cb + ch + lro];
    }
    ASM_VMCNT(4);  // forces next-tile s0 done -> safe for next P0 reads
    SBAR();
    __builtin_amdgcn_s_setprio(1);
#pragma unroll
    for (int mf = 0; mf < 4; ++mf)
#pragma unroll
      for (int nf = 0; nf < 2; ++nf) {
        acc[mf][nf] = MFMA32(ah[mf], bh[nf], acc[mf][nf]);
        acc[mf][nf] = MFMA32(ah[mf], bl[nf], acc[mf][nf]);
        acc[mf][nf] = MFMA32(al[mf], bh[nf], acc[mf][nf]);
      }
    __builtin_amdgcn_s_setprio(0);
    SBAR();
  }

  // epilogue: BN (1/1024 folded) + leaky, split to fp16 hi/lo, store NHWC.
  // 32x32 C/D: col = lane&31, row = (reg&3) + 8*(reg>>2) + 4*(lane>>5)
#pragma unroll
  for (int mf = 0; mf < 4; ++mf) {
#pragma unroll
    for (int nf = 0; nf < 2; ++nf) {
      const int colB = n0 + wn * 64 + nf * 32 + l31;
      const long colOff = (long)colB * 1024;
#pragma unroll
      for (int rg = 0; rg < 4; ++rg) {
        const int cob = co0 + wm * 128 + mf * 32 + rg * 8 + lh * 4;
        const float4 scv = *(const float4*)(scale + cob);
        const float4 shv = *(const float4*)(shift + cob);
        float v0 = acc[mf][nf][rg * 4 + 0] * scv.x + shv.x; v0 = v0 > 0.f ? v0 : 0.1f * v0;
        float v1 = acc[mf][nf][rg * 4 + 1] * scv.y + shv.y; v1 = v1 > 0.f ? v1 : 0.1f * v1;
        float v2 = acc[mf][nf][rg * 4 + 2] * scv.z + shv.z; v2 = v2 > 0.f ? v2 : 0.1f * v2;
        float v3 = acc[mf][nf][rg * 4 + 3] * scv.w + shv.w; v3 = v3 > 0.f ? v3 : 0.1f * v3;
        f16 h0 = (f16)v0, h1 = (f16)v1, h2 = (f16)v2, h3 = (f16)v3;
        f16x4v hv = {h0, h1, h2, h3};
        f16x4v lv = {(f16)(v0 - (float)h0), (f16)(v1 - (float)h1),
                     (f16)(v2 - (float)h2), (f16)(v3 - (float)h3)};
        *(f16x4v*)(xth + colOff + cob) = hv;
        *(f16x4v*)(xtl + colOff + cob) = lv;
      }
    }
  }
}

// ---------------------------------------------------------------------------
// gemm2: preds[n][512] = A2(512x1024) * xt (+bias, /1024). Same structure.
// grid (128 n-tiles, 2 m-tiles), block 512. K-tiles = 32.
// ---------------------------------------------------------------------------
__global__ __launch_bounds__(512, 2) void gemm2(
    const f16* __restrict__ A2h, const f16* __restrict__ A2l,
    const f16* __restrict__ Bh, const f16* __restrict__ Bl,
    const float* __restrict__ bias, float* __restrict__ preds) {
  __shared__ __align__(16) f16 S[65536];
  const int tid = threadIdx.x;
  const int l = tid & 63, w = tid >> 6;
  const int wm = w >> 2, wn = w & 3;
  const int l31 = l & 31, lh = l >> 5;
  const int nt = blockIdx.x, mt = blockIdx.y;
  const int n0 = nt * 256, co0 = mt * 256;

  const long aSrc = (long)(co0 + 32 * w + l31) * 1024 + 8 * lh;
  const long bSrc = (long)(n0 + 32 * w + l31) * 1024 + 8 * lh;
  const int dA = (w * 2) * 512;
  const int lro = l * 8;

  f32x16 acc[4][2] = {};
  f16x8 ah[4], al[4], bh[2], bl[2];

  gload16(A2h + aSrc, &S[R_AH + dA]);
  gload16(A2l + aSrc, &S[R_AL + dA]);
  gload16(Bh + bSrc, &S[R_BH + dA]);
  gload16(Bl + bSrc, &S[R_BL + dA]);
  gload16(A2h + aSrc + 16, &S[R_AH + dA + 512]);
  gload16(A2l + aSrc + 16, &S[R_AL + dA + 512]);
  gload16(Bh + bSrc + 16, &S[R_BH + dA + 512]);
  gload16(Bl + bSrc + 16, &S[R_BL + dA + 512]);
  ASM_VMCNT(4);
  SBAR();

  for (int t = 0; t < 32; ++t) {
    const int cb = (t & 1) << 13;
    const int nb = 8192 - cb;
    const long kn = (long)((t < 31) ? t + 1 : t) * 32;

    // ======== P0 ========
    gload16(A2h + aSrc + kn, &S[R_AH + nb + dA]);
    gload16(A2l + aSrc + kn, &S[R_AL + nb + dA]);
    gload16(Bh + bSrc + kn, &S[R_BH + nb + dA]);
    gload16(Bl + bSrc + kn, &S[R_BL + nb + dA]);
#pragma unroll
    for (int mf = 0; mf < 4; ++mf) {
      const int ch = ((wm * 4 + mf) * 2) * 512;
      ah[mf] = *(const f16x8*)&S[R_AH + cb + ch + lro];
      al[mf] = *(const f16x8*)&S[R_AL + cb + ch + lro];
    }
#pragma unroll
    for (int nf = 0; nf < 2; ++nf) {
      const int ch = ((wn * 2 + nf) * 2) * 512;
      bh[nf] = *(const f16x8*)&S[R_BH + cb + ch + lro];
      bl[nf] = *(const f16x8*)&S[R_BL + cb + ch + lro];
    }
    ASM_VMCNT(4);
    SBAR();
    __builtin_amdgcn_s_setprio(1);
#pragma unroll
    for (int mf = 0; mf < 4; ++mf)
#pragma unroll
      for (int nf = 0; nf < 2; ++nf) {
        acc[mf][nf] = MFMA32(ah[mf], bh[nf], acc[mf][nf]);
        acc[mf][nf] = MFMA32(ah[mf], bl[nf], acc[mf][nf]);
        acc[mf][nf] = MFMA32(al[mf], bh[nf], acc[mf][nf]);
      }
    __builtin_amdgcn_s_setprio(0);
    SBAR();

    // ======== P1 ========
    gload16(A2h + aSrc + kn + 16, &S[R_AH + nb + dA + 512]);
    gload16(A2l + aSrc + kn + 16, &S[R_AL + nb + dA + 512]);
    gload16(Bh + bSrc + kn + 16, &S[R_BH + nb + dA + 512]);
    gload16(Bl + bSrc + kn + 16, &S[R_BL + nb + dA + 512]);
#pragma unroll
    for (int mf = 0; mf < 4; ++mf) {
      const int ch = ((wm * 4 + mf) * 2 + 1) * 512;
      ah[mf] = *(const f16x8*)&S[R_AH + cb + ch + lro];
      al[mf] = *(const f16x8*)&S[R_AL + cb + ch + lro];
    }
#pragma unroll
    for (int nf = 0; nf < 2; ++nf) {
      const int ch = ((wn * 2 + nf) * 2 + 1) * 512;
      bh[nf] = *(const f16x8*)&S[R_BH + cb + ch + lro];
      bl[nf] = *(const f16x8*)&S[R_BL + cb + ch + lro];
    }
    ASM_VMCNT(4);
    SBAR();
    __builtin_amdgcn_s_setprio(1);
#pragma unroll
    for (int mf = 0; mf < 4; ++mf)
#pragma unroll
      for (int nf = 0; nf < 2; ++nf) {
        acc[mf][nf] = MFMA32(ah[mf], bh[nf], acc[mf][nf]);
        acc[mf][nf] = MFMA32(ah[mf], bl[nf], acc[mf][nf]);
        acc[mf][nf] = MFMA32(al[mf], bh[nf], acc[mf][nf]);
      }
    __builtin_amdgcn_s_setprio(0);
    SBAR();
  }

#pragma unroll
  for (int mf = 0; mf < 4; ++mf) {
#pragma unroll
    for (int nf = 0; nf < 2; ++nf) {
      const int colB = n0 + wn * 64 + nf * 32 + l31;
      const long colOff = (long)colB * 512;
#pragma unroll
      for (int rg = 0; rg < 4; ++rg) {
        const int cob = co0 + wm * 128 + mf * 32 + rg * 8 + lh * 4;
        const float4 bi = *(const float4*)(bias + cob);
        float4 o;
        o.x = acc[mf][nf][rg * 4 + 0] * 9.765625e-4f + bi.x;
        o.y = acc[mf][nf][rg * 4 + 1] * 9.765625e-4f + bi.y;
        o.z = acc[mf][nf][rg * 4 + 2] * 9.765625e-4f + bi.z;
        o.w = acc[mf][nf][rg * 4 + 3] * 9.765625e-4f + bi.w;
        *(float4*)(preds + colOff + cob) = o;
      }
    }
  }
}

// ---------------------------------------------------------------------------
__global__ __launch_bounds__(256) void decode(const float* __restrict__ preds,
                                              float* __restrict__ out) {
  const int t = blockIdx.x * 256 + threadIdx.x;  // < 163840
  const int b = t / 5120, rem = t % 5120, pos = rem / 5, a = rem % 5;
  const int n = (b << 10) + pos;
  const float* p = preds + (long)n * 512 + a * 85;

  float tx = p[0], ty = p[1], tw = p[2], th = p[3], to = p[4];
  float mx = p[5];
  int arg = 0;
  for (int i = 1; i < 80; ++i) {
    float v = p[5 + i];
    if (v > mx) { mx = v; arg = i; }
  }
  float sum = 0.f;
  for (int i = 0; i < 80; ++i) sum += expf(p[5 + i] - mx);

  float obj = 1.f / (1.f + expf(-to));
  float score = obj / sum;
  float bx = 1.f / (1.f + expf(-tx));
  float by = 1.f / (1.f + expf(-ty));
  float bw = expf(fminf(tw, 8.f));
  float bh2 = expf(fminf(th, 8.f));
  float cx = (bx + (float)(pos & 31)) * 32.f;
  float cy = (by + (float)(pos >> 5)) * 32.f;
  float pw = c_AW[a] * bw;
  float ph = c_AH_[a] * bh2;
  float x1 = fminf(fmaxf(cx - 0.5f * pw, 0.f), 1023.f);
  float y1 = fminf(fmaxf(cy - 0.5f * ph, 0.f), 1023.f);
  float x2 = fminf(fmaxf(cx + 0.5f * pw, 0.f), 1023.f);
  float y2 = fminf(fmaxf(cy + 0.5f * ph, 0.f), 1023.f);

  const long o = ((long)b * 5120 + pos * 5 + a) * 5;
  out[o + 0] = x1;
  out[o + 1] = y1;
  out[o + 2] = x2;
  out[o + 3] = y2;
  out[o + 4] = score;
  out[819200 + (long)b * 5120 + pos * 5 + a] = (float)arg;
}

// ---------------------------------------------------------------------------
// workspace layout (bytes):
//   0          fph  [32][34][34][512] f16   37,879,808
//   37879808   fpl                          37,879,808
//   75759616   A1h  [1024][4608] f16         9,437,184
//   85196800   A1l                           9,437,184
//   94633984   A2h  [512][1024] f16          1,048,576
//   95682560   A2l                           1,048,576
//   96731136   scale f32[1024]                   4,096
//   96735232   shift f32[1024]                   4,096
//   96739328   bias  f32[512]                    2,048
//   96741376   xth  [32768][1024] f16       67,108,864
//   163850240  xtl                          67,108,864
//   total 230,959,104;  preds f32[32768][512] aliases offset 0
// ---------------------------------------------------------------------------
extern "C" void kernel_launch(void* const* d_in, const int* in_sizes, int n_in,
                              void* d_out, int out_size, void* d_ws, size_t ws_size,
                              hipStream_t stream) {
  (void)in_sizes; (void)n_in; (void)out_size; (void)ws_size;
  const float* features = (const float*)d_in[0];
  const float* conv1_w = (const float*)d_in[1];
  const float* bn_g = (const float*)d_in[2];
  const float* bn_b = (const float*)d_in[3];
  const float* bn_m = (const float*)d_in[4];
  const float* bn_v = (const float*)d_in[5];
  const float* conv2_w = (const float*)d_in[6];
  const float* conv2_b = (const float*)d_in[7];
  float* out = (float*)d_out;
  char* ws = (char*)d_ws;

  f16* fph = (f16*)(ws + 0);
  f16* fpl = (f16*)(ws + 37879808L);
  f16* A1h = (f16*)(ws + 75759616L);
  f16* A1l = (f16*)(ws + 85196800L);
  f16* A2h = (f16*)(ws + 94633984L);
  f16* A2l = (f16*)(ws + 95682560L);
  float* scale = (float*)(ws + 96731136L);
  float* shift = (float*)(ws + 96735232L);
  float* bias = (float*)(ws + 96739328L);
  f16* xth = (f16*)(ws + 96741376L);
  f16* xtl = (f16*)(ws + 163850240L);
  float* preds = (float*)(ws + 0);  // alias: fp dead after gemm1

  hipMemsetAsync(ws, 0, 75759616L, stream);  // zero padded feature rings
  prep_misc<<<1, 1024, 0, stream>>>(bn_g, bn_b, bn_m, bn_v, conv2_b, scale, shift, bias);
  prep_w1<<<dim3(1024, 18), 256, 0, stream>>>(conv1_w, A1h, A1l);
  prep_w2<<<dim3(512, 4), 256, 0, stream>>>(conv2_w, A2h, A2l);
  prep_feat<<<dim3(32, 32), 256, 0, stream>>>(features, fph, fpl);
  gemm1<<<dim3(128, 4), 512, 0, stream>>>(A1h, A1l, fph, fpl, scale, shift, xth, xtl);
  gemm2<<<dim3(128, 2), 512, 0, stream>>>(A2h, A2l, xth, xtl, bias, preds);
  decode<<<640, 256, 0, stream>>>(preds, out);
}